// Round 14
// baseline (51.507 us; speedup 1.0000x reference)
//
#include <hip/hip_runtime.h>
#include <math.h>

#define NB 256
#define NV 6890
#define NF 13776
#define NFP 16384               // faces padded to 4 * 4096, pad part = 15
#define NHD 20000
#define NHDP 20480              // samples padded to 5 * 4096, pad mask = 0
#define NPARTS 10
#define PY 120
#define PX 40
#define THREADS 1024
#define NWAVES (THREADS / 64)

// d_ws layout (bytes):
//   [0, 1024)            : per-batch distances (NB floats)
//   [1024, +NFP*16)      : face table   int4{i0,i1,i2,part}   (pads part=15)
//   [.., +NHDP*16)       : sample table int4{i0,i1,i2,part}   (pads {0,0,0,0})
//   [.., +NHDP*16)       : sample bary  float4{w0,w1,w2,mask} (pads mask=0)
#define WS_DIST_OFF  0
#define WS_TABF_OFF  1024
#define WS_TABS_OFF  (WS_TABF_OFF + NFP * 16)
#define WS_TABW_OFF  (WS_TABS_OFF + NHDP * 16)
#define WS_NEEDED    (WS_TABW_OFF + NHDP * 16)

__device__ __forceinline__ float wred(float v) {
#pragma unroll
    for (int off = 32; off; off >>= 1) v += __shfl_down(v, off, 64);
    return v;
}

__global__ __launch_bounds__(256) void build_tabs(const int* __restrict__ faces,
                                                  const int* __restrict__ face_part,
                                                  const int* __restrict__ face_sample,
                                                  const float* __restrict__ bary_w,
                                                  int4* __restrict__ tabF,
                                                  int4* __restrict__ tabS,
                                                  float4* __restrict__ tabW) {
    const int i = blockIdx.x * 256 + threadIdx.x;
    if (i < NF)
        tabF[i] = make_int4(faces[3 * i + 0], faces[3 * i + 1], faces[3 * i + 2], face_part[i]);
    else if (i < NFP)
        tabF[i] = make_int4(0, 0, 0, 15);            // pad: slot 15 never read
    if (i < NHD) {
        const int fs = face_sample[i];
        tabS[i] = make_int4(faces[3 * fs + 0], faces[3 * fs + 1], faces[3 * fs + 2],
                            face_part[fs]);
        tabW[i] = make_float4(bary_w[3 * i + 0], bary_w[3 * i + 1], bary_w[3 * i + 2], 1.0f);
    } else if (i < NHDP) {
        tabS[i] = make_int4(0, 0, 0, 0);
        tabW[i] = make_float4(0.0f, 0.0f, 0.0f, 0.0f);   // mask=0: contributes nothing
    }
}

__device__ __forceinline__ float tet_of(const float2* __restrict__ svxy,
                                        const float* __restrict__ svz, int4 q) {
    const float2 a = svxy[q.x];
    const float2 b = svxy[q.y];
    const float2 c = svxy[q.z];
    const float az = svz[q.x], bz = svz[q.y], cz = svz[q.z];
    return (a.x * (b.y * cz - bz * c.y) + a.y * (bz * c.x - b.x * cz) +
            az * (b.x * c.y - b.y * c.x)) * (1.0f / 6.0f);
}

template <bool TAB>
__global__ __launch_bounds__(THREADS, 4) void stab_main(
    const float* __restrict__ vertices,    // [NB, NV, 3]
    const float* __restrict__ pressure,    // [NB, PY, PX]
    const float* __restrict__ bary_w,      // [NHD, 3]
    const int*   __restrict__ faces,       // [NF, 3]
    const int*   __restrict__ face_sample, // [NHD]
    const int*   __restrict__ face_part,   // [NF]
    const int4*  __restrict__ tabF,        // [NFP]
    const int4*  __restrict__ tabS,        // [NHDP]
    const float4* __restrict__ tabW,       // [NHDP]
    float* __restrict__ out,
    float* __restrict__ dist)
{
    const int b    = blockIdx.x;
    const int tid  = threadIdx.x;
    const int wave = tid >> 6;
    const int lane = tid & 63;

    __shared__ float2 svxy[NV];           // 55120 B: b64 gathers
    __shared__ float  svz[NV];            // 27560 B
    __shared__ float  red[NWAVES][12];
    __shared__ float  ppv[NPARTS];        // broadcast reads: conflict-free
    __shared__ float  ppw[NWAVES][16];    // per-wave part accumulators (slot 15 = pad sink)

    // ---- init per-wave part accumulators ----
    if (tid < NWAVES * 16) ((float*)ppw)[tid] = 0.0f;

    // ---- stage vertices[b] into LDS (xy packed, z separate) ----
    const float* vb = vertices + (size_t)b * (NV * 3);
    for (int v = tid; v < NV; v += THREADS) {
        svxy[v] = make_float2(vb[3 * v + 0], vb[3 * v + 1]);
        svz[v]  = vb[3 * v + 2];
    }
    __syncthreads();

    // ---- Phase A: tet volumes -> per-wave LDS segment add (no select chain) ----
    if constexpr (TAB) {
        for (int f0 = tid; f0 < NFP; f0 += 4 * THREADS) {
            const int4 q0 = tabF[f0];
            const int4 q1 = tabF[f0 + THREADS];
            const int4 q2 = tabF[f0 + 2 * THREADS];
            const int4 q3 = tabF[f0 + 3 * THREADS];
            const float t0 = tet_of(svxy, svz, q0);
            const float t1 = tet_of(svxy, svz, q1);
            const float t2 = tet_of(svxy, svz, q2);
            const float t3 = tet_of(svxy, svz, q3);
            // per-wave segment: cross-wave order never interleaves; within one
            // ds_add instruction same-address lanes serialize in fixed lane order
            // -> deterministic
            atomicAdd(&ppw[wave][q0.w], t0);
            atomicAdd(&ppw[wave][q1.w], t1);
            atomicAdd(&ppw[wave][q2.w], t2);
            atomicAdd(&ppw[wave][q3.w], t3);
        }
        __syncthreads();
        if (tid < NPARTS) {
            float s = 0.0f;
#pragma unroll
            for (int w = 0; w < NWAVES; ++w) s += ppw[w][tid];
            ppv[tid] = s;
        }
        __syncthreads();
    } else {
        float pv[NPARTS];
#pragma unroll
        for (int p = 0; p < NPARTS; ++p) pv[p] = 0.0f;
        for (int f = tid; f < NF; f += THREADS) {
            const int4 q = make_int4(faces[3 * f + 0], faces[3 * f + 1], faces[3 * f + 2],
                                     face_part[f]);
            const float t = tet_of(svxy, svz, q);
#pragma unroll
            for (int p = 0; p < NPARTS; ++p) pv[p] += (q.w == p) ? t : 0.0f;
        }
#pragma unroll
        for (int p = 0; p < NPARTS; ++p) {
            const float r = wred(pv[p]);
            if (lane == 0) red[wave][p] = r;
        }
        __syncthreads();
        if (tid < NPARTS) {
            float s = 0.0f;
#pragma unroll
            for (int w = 0; w < NWAVES; ++w) s += red[w][tid];
            ppv[tid] = s;
        }
        __syncthreads();
    }

    // ---- Phase B: blended samples -> COM + weighted-CoP sums ----
    float cnx = 0.f, cny = 0.f, cd = 0.f;
    float pnx = 0.f, pny = 0.f, pd = 0.f;
    const float KEXP = -14.426950408889634f;   // -10 * log2(e)

    if constexpr (TAB) {
        for (int n0 = tid; n0 < NHDP; n0 += 4 * THREADS) {
            const int4   q0 = tabS[n0];
            const int4   q1 = tabS[n0 + THREADS];
            const int4   q2 = tabS[n0 + 2 * THREADS];
            const int4   q3 = tabS[n0 + 3 * THREADS];
            const float4 w0 = tabW[n0];
            const float4 w1 = tabW[n0 + THREADS];
            const float4 w2 = tabW[n0 + 2 * THREADS];
            const float4 w3 = tabW[n0 + 3 * THREADS];

            const float2 a0 = svxy[q0.x], b0 = svxy[q0.y], c0 = svxy[q0.z];
            const float2 a1 = svxy[q1.x], b1 = svxy[q1.y], c1 = svxy[q1.z];
            const float2 a2 = svxy[q2.x], b2 = svxy[q2.y], c2 = svxy[q2.z];
            const float2 a3 = svxy[q3.x], b3 = svxy[q3.y], c3 = svxy[q3.z];

            const float hx0 = w0.x * a0.x + w0.y * b0.x + w0.z * c0.x;
            const float hy0 = w0.x * a0.y + w0.y * b0.y + w0.z * c0.y;
            const float hx1 = w1.x * a1.x + w1.y * b1.x + w1.z * c1.x;
            const float hy1 = w1.x * a1.y + w1.y * b1.y + w1.z * c1.y;
            const float hx2 = w2.x * a2.x + w2.y * b2.x + w2.z * c2.x;
            const float hy2 = w2.x * a2.y + w2.y * b2.y + w2.z * c2.y;
            const float hx3 = w3.x * a3.x + w3.y * b3.x + w3.z * c3.x;
            const float hy3 = w3.x * a3.y + w3.y * b3.y + w3.z * c3.y;

            const float vol0 = ppv[q0.w] * w0.w;
            const float vol1 = ppv[q1.w] * w1.w;
            const float vol2 = ppv[q2.w] * w2.w;
            const float vol3 = ppv[q3.w] * w3.w;

            const float pw0 = ((hy0 < 0.0f) ? (1.0f - 100.0f * hy0) : exp2f(KEXP * hy0)) * w0.w;
            const float pw1 = ((hy1 < 0.0f) ? (1.0f - 100.0f * hy1) : exp2f(KEXP * hy1)) * w1.w;
            const float pw2 = ((hy2 < 0.0f) ? (1.0f - 100.0f * hy2) : exp2f(KEXP * hy2)) * w2.w;
            const float pw3 = ((hy3 < 0.0f) ? (1.0f - 100.0f * hy3) : exp2f(KEXP * hy3)) * w3.w;

            cnx += hx0 * vol0 + hx1 * vol1 + hx2 * vol2 + hx3 * vol3;
            cny += hy0 * vol0 + hy1 * vol1 + hy2 * vol2 + hy3 * vol3;
            cd  += vol0 + vol1 + vol2 + vol3;
            pnx += hx0 * pw0 + hx1 * pw1 + hx2 * pw2 + hx3 * pw3;
            pny += hy0 * pw0 + hy1 * pw1 + hy2 * pw2 + hy3 * pw3;
            pd  += pw0 + pw1 + pw2 + pw3;
        }
    } else {
        for (int n = tid; n < NHD; n += THREADS) {
            const int fs = face_sample[n];
            const int i0 = faces[3 * fs + 0], i1 = faces[3 * fs + 1], i2 = faces[3 * fs + 2];
            const float w0 = bary_w[3 * n + 0], w1 = bary_w[3 * n + 1], w2 = bary_w[3 * n + 2];
            const float2 a = svxy[i0], bb = svxy[i1], c = svxy[i2];
            const float hx = w0 * a.x + w1 * bb.x + w2 * c.x;
            const float hy = w0 * a.y + w1 * bb.y + w2 * c.y;
            const float vol = ppv[face_part[fs]];
            cnx += hx * vol; cny += hy * vol; cd += vol;
            const float pw = (hy < 0.0f) ? (1.0f - 100.0f * hy) : exp2f(KEXP * hy);
            pnx += hx * pw; pny += hy * pw; pd += pw;
        }
    }

    // ---- pressure moments (float4) ----
    float pt = 0.f, pxs = 0.f, pys = 0.f;
    const float4* pb4 = (const float4*)(pressure + (size_t)b * (PY * PX));
    for (int i = tid; i < (PY * PX) / 4; i += THREADS) {
        const float4 v = pb4[i];
        const int idx = 4 * i;
        const float xb = (float)(idx % PX);
        const float yb = (float)(idx / PX);
        const float srow = v.x + v.y + v.z + v.w;
        pt  += srow;
        pxs += v.x * xb + v.y * (xb + 1.0f) + v.z * (xb + 2.0f) + v.w * (xb + 3.0f);
        pys += srow * yb;
    }

    // ---- block reduction of 9 scalars ----
    float vals[9] = {cnx, cny, cd, pnx, pny, pd, pt, pxs, pys};
#pragma unroll
    for (int k = 0; k < 9; ++k) {
        const float r = wred(vals[k]);
        if (lane == 0) red[wave][k] = r;
    }
    __syncthreads();

    if (tid == 0) {
        float s[9];
#pragma unroll
        for (int k = 0; k < 9; ++k) {
            float acc = 0.0f;
#pragma unroll
            for (int w = 0; w < NWAVES; ++w) acc += red[w][k];
            s[k] = acc;
        }
        const float comx  = s[0] / s[2];
        const float comy  = s[1] / s[2];
        const float copx  = s[3] / (s[5] + 1e-6f);
        const float copy_ = s[4] / (s[5] + 1e-6f);

        out[1 + 2 * b + 0] = comx * 48.0f;
        out[1 + 2 * b + 1] = (59.0f / 33.0f - comy) * 33.0f;
        out[1 + 2 * NB + 2 * b + 0] = (copx + 18.0f / 78.74f) * (100.0f * 0.7874f);
        out[1 + 2 * NB + 2 * b + 1] = (86.0f / 78.74f - copy_) * (100.0f * 0.7874f);

        const float total = (s[6] == 0.0f) ? 1e-8f : s[6];
        const float xc = s[7] / total;
        const float yc = s[8] / total;
        const float pcopx = 0.01f * (xc - 18.0f) / 0.7874f;
        const float pcopy = 0.01f * (86.0f - yc) / 0.7874f;

        const float dx = comx - pcopx;
        const float dy = comy - pcopy;
        dist[b] = sqrtf(dx * dx + dy * dy);
    }
}

__global__ __launch_bounds__(256) void stab_reduce(const float* __restrict__ dist,
                                                   float* __restrict__ out) {
    const int tid = threadIdx.x;
    float v = dist[tid];
    v = wred(v);
    __shared__ float red[4];
    if ((tid & 63) == 0) red[tid >> 6] = v;
    __syncthreads();
    if (tid == 0) out[0] = (red[0] + red[1] + red[2] + red[3]) * (1.0f / 256.0f);
}

extern "C" void kernel_launch(void* const* d_in, const int* in_sizes, int n_in,
                              void* d_out, int out_size, void* d_ws, size_t ws_size,
                              hipStream_t stream) {
    const float* vertices    = (const float*)d_in[0];
    const float* pressure    = (const float*)d_in[1];
    const float* bary_w      = (const float*)d_in[2];
    const int*   faces       = (const int*)d_in[3];
    const int*   face_sample = (const int*)d_in[4];
    const int*   face_part   = (const int*)d_in[5];
    float* out = (float*)d_out;
    char*  ws  = (char*)d_ws;

    float* dist = (float*)(ws + WS_DIST_OFF);

    if (ws_size >= (size_t)WS_NEEDED) {
        int4*   tabF = (int4*)(ws + WS_TABF_OFF);
        int4*   tabS = (int4*)(ws + WS_TABS_OFF);
        float4* tabW = (float4*)(ws + WS_TABW_OFF);
        build_tabs<<<(NHDP + 255) / 256, 256, 0, stream>>>(faces, face_part, face_sample,
                                                           bary_w, tabF, tabS, tabW);
        stab_main<true><<<NB, THREADS, 0, stream>>>(vertices, pressure, bary_w, faces,
                                                    face_sample, face_part, tabF, tabS, tabW,
                                                    out, dist);
    } else {
        stab_main<false><<<NB, THREADS, 0, stream>>>(vertices, pressure, bary_w, faces,
                                                     face_sample, face_part, nullptr, nullptr,
                                                     nullptr, out, dist);
    }
    stab_reduce<<<1, 256, 0, stream>>>(dist, out);
}

// Round 15
// 42.331 us; speedup vs baseline: 1.2168x; 1.2168x over previous
//
#include <hip/hip_runtime.h>
#include <math.h>

#define NB 256
#define NV 6890
#define NF 13776
#define NFP 16384               // faces padded to 4 * 4096, pad part = 15
#define NHD 20000
#define NHDP 20480              // samples padded, pad mask = 0
#define NPARTS 10
#define PY 120
#define PX 40

// ws layout (bytes):
//   [0, 16384)       : acc[NB][16]  (ppv[0..9], pt, pxs, pys)
//   [16384, 28672)   : pB[6][512]   (cnx,cny,cd,pnx,pny,pd per (batch,half))
//   [32768, +NFP*16) : tabF int4{i0,i1,i2,part} (pads part=15)
//   [.., +NHDP*16)   : tabS int4 (pads {0,0,0,0})
//   [.., +NHDP*16)   : tabW float4{w0,w1,w2,mask} (pads mask=0)
#define WS_ACC_OFF   0
#define WS_PB_OFF    16384
#define WS_TABF_OFF  32768
#define WS_TABS_OFF  (WS_TABF_OFF + NFP * 16)
#define WS_TABW_OFF  (WS_TABS_OFF + NHDP * 16)
#define WS_NEEDED    (WS_TABW_OFF + NHDP * 16)

__device__ __forceinline__ float wred(float v) {
#pragma unroll
    for (int off = 32; off; off >>= 1) v += __shfl_down(v, off, 64);
    return v;
}

__global__ __launch_bounds__(256) void build_tabs(const int* __restrict__ faces,
                                                  const int* __restrict__ face_part,
                                                  const int* __restrict__ face_sample,
                                                  const float* __restrict__ bary_w,
                                                  int4* __restrict__ tabF,
                                                  int4* __restrict__ tabS,
                                                  float4* __restrict__ tabW) {
    const int i = blockIdx.x * 256 + threadIdx.x;
    if (i < NF)
        tabF[i] = make_int4(faces[3 * i + 0], faces[3 * i + 1], faces[3 * i + 2], face_part[i]);
    else if (i < NFP)
        tabF[i] = make_int4(0, 0, 0, 15);            // pad: part 15 never accumulated
    if (i < NHD) {
        const int fs = face_sample[i];
        tabS[i] = make_int4(faces[3 * fs + 0], faces[3 * fs + 1], faces[3 * fs + 2],
                            face_part[fs]);
        tabW[i] = make_float4(bary_w[3 * i + 0], bary_w[3 * i + 1], bary_w[3 * i + 2], 1.0f);
    } else if (i < NHDP) {
        tabS[i] = make_int4(0, 0, 0, 0);
        tabW[i] = make_float4(0.0f, 0.0f, 0.0f, 0.0f);   // mask=0: contributes nothing
    }
}

__device__ __forceinline__ float tet_of(const float2* __restrict__ svxy,
                                        const float* __restrict__ svz, int4 q) {
    const float2 a = svxy[q.x];
    const float2 b = svxy[q.y];
    const float2 c = svxy[q.z];
    const float az = svz[q.x], bz = svz[q.y], cz = svz[q.z];
    return (a.x * (b.y * cz - bz * c.y) + a.y * (bz * c.x - b.x * cz) +
            az * (b.x * c.y - b.y * c.x)) * (1.0f / 6.0f);
}

// ---- kA: full xyz in LDS (1 blk/CU), Phase A tet volumes + pressure moments ----
__global__ __launch_bounds__(1024, 4) void kA(const float* __restrict__ vertices,
                                              const float* __restrict__ pressure,
                                              const int4* __restrict__ tabF,
                                              float* __restrict__ acc) {
    const int b    = blockIdx.x;
    const int tid  = threadIdx.x;
    const int wave = tid >> 6;
    const int lane = tid & 63;

    __shared__ float2 svxy[NV];           // 55120 B
    __shared__ float  svz[NV];            // 27560 B
    __shared__ float  red[16][13];

    const float* vb = vertices + (size_t)b * (NV * 3);
    for (int v = tid; v < NV; v += 1024) {
        svxy[v] = make_float2(vb[3 * v + 0], vb[3 * v + 1]);
        svz[v]  = vb[3 * v + 2];
    }
    __syncthreads();

    float pv[NPARTS];
#pragma unroll
    for (int p = 0; p < NPARTS; ++p) pv[p] = 0.0f;

    for (int f0 = tid; f0 < NFP; f0 += 4096) {
        const int4 q0 = tabF[f0];
        const int4 q1 = tabF[f0 + 1024];
        const int4 q2 = tabF[f0 + 2048];
        const int4 q3 = tabF[f0 + 3072];
        const float t0 = tet_of(svxy, svz, q0);
        const float t1 = tet_of(svxy, svz, q1);
        const float t2 = tet_of(svxy, svz, q2);
        const float t3 = tet_of(svxy, svz, q3);
#pragma unroll
        for (int p = 0; p < NPARTS; ++p) {
            pv[p] += (q0.w == p) ? t0 : 0.0f;
            pv[p] += (q1.w == p) ? t1 : 0.0f;
            pv[p] += (q2.w == p) ? t2 : 0.0f;
            pv[p] += (q3.w == p) ? t3 : 0.0f;
        }
    }

    // pressure moments
    float pt = 0.f, pxs = 0.f, pys = 0.f;
    const float4* pb4 = (const float4*)(pressure + (size_t)b * (PY * PX));
    for (int i = tid; i < (PY * PX) / 4; i += 1024) {
        const float4 v = pb4[i];
        const int idx = 4 * i;
        const float xb = (float)(idx % PX);
        const float yb = (float)(idx / PX);
        const float srow = v.x + v.y + v.z + v.w;
        pt  += srow;
        pxs += v.x * xb + v.y * (xb + 1.0f) + v.z * (xb + 2.0f) + v.w * (xb + 3.0f);
        pys += srow * yb;
    }

    float vals[13] = {pv[0], pv[1], pv[2], pv[3], pv[4], pv[5], pv[6], pv[7], pv[8], pv[9],
                      pt, pxs, pys};
#pragma unroll
    for (int k = 0; k < 13; ++k) {
        const float r = wred(vals[k]);
        if (lane == 0) red[wave][k] = r;
    }
    __syncthreads();
    if (tid < 13) {
        float s = 0.0f;
#pragma unroll
        for (int w = 0; w < 16; ++w) s += red[w][tid];
        acc[b * 16 + tid] = s;
    }
}

// ---- kB: xy-only LDS (2 blk/CU, 32 waves), Phase B samples, half per block ----
__global__ __launch_bounds__(1024, 8) void kB(const float* __restrict__ vertices,
                                              const int4*  __restrict__ tabS,
                                              const float4* __restrict__ tabW,
                                              const float* __restrict__ acc,
                                              float* __restrict__ pB) {
    const int bid  = blockIdx.x;
    const int b    = bid >> 1;
    const int half = bid & 1;
    const int tid  = threadIdx.x;
    const int wave = tid >> 6;
    const int lane = tid & 63;

    __shared__ float2 svxy[NV];           // 55120 B -> 2 blocks/CU
    __shared__ float  red[16][6];
    __shared__ float  ppv[NPARTS];

    const float* vb = vertices + (size_t)b * (NV * 3);
    for (int v = tid; v < NV; v += 1024)
        svxy[v] = make_float2(vb[3 * v + 0], vb[3 * v + 1]);
    if (tid < NPARTS) ppv[tid] = acc[b * 16 + tid];
    __syncthreads();

    float cnx = 0.f, cny = 0.f, cd = 0.f;
    float pnx = 0.f, pny = 0.f, pd = 0.f;
    const float KEXP = -14.426950408889634f;   // -10 * log2(e)

    const int nbase = half * (NHDP / 2);
    for (int n0 = nbase + tid; n0 < nbase + NHDP / 2; n0 += 2048) {   // 5 iters, 2-wide
        const int4   q0 = tabS[n0];
        const int4   q1 = tabS[n0 + 1024];
        const float4 w0 = tabW[n0];
        const float4 w1 = tabW[n0 + 1024];

        const float2 a0 = svxy[q0.x], b0 = svxy[q0.y], c0 = svxy[q0.z];
        const float2 a1 = svxy[q1.x], b1 = svxy[q1.y], c1 = svxy[q1.z];

        const float hx0 = w0.x * a0.x + w0.y * b0.x + w0.z * c0.x;
        const float hy0 = w0.x * a0.y + w0.y * b0.y + w0.z * c0.y;
        const float hx1 = w1.x * a1.x + w1.y * b1.x + w1.z * c1.x;
        const float hy1 = w1.x * a1.y + w1.y * b1.y + w1.z * c1.y;

        const float vol0 = ppv[q0.w] * w0.w;
        const float vol1 = ppv[q1.w] * w1.w;

        const float pw0 = ((hy0 < 0.0f) ? (1.0f - 100.0f * hy0) : exp2f(KEXP * hy0)) * w0.w;
        const float pw1 = ((hy1 < 0.0f) ? (1.0f - 100.0f * hy1) : exp2f(KEXP * hy1)) * w1.w;

        cnx += hx0 * vol0 + hx1 * vol1;
        cny += hy0 * vol0 + hy1 * vol1;
        cd  += vol0 + vol1;
        pnx += hx0 * pw0 + hx1 * pw1;
        pny += hy0 * pw0 + hy1 * pw1;
        pd  += pw0 + pw1;
    }

    float vals[6] = {cnx, cny, cd, pnx, pny, pd};
#pragma unroll
    for (int k = 0; k < 6; ++k) {
        const float r = wred(vals[k]);
        if (lane == 0) red[wave][k] = r;
    }
    __syncthreads();
    if (tid < 6) {
        float s = 0.0f;
#pragma unroll
        for (int w = 0; w < 16; ++w) s += red[w][tid];
        pB[tid * 512 + bid] = s;
    }
}

// ---- finish: combine halves (2-addend sums: order-independent), outputs + mean ----
__global__ __launch_bounds__(256) void stab_finish(const float* __restrict__ acc,
                                                   const float* __restrict__ pB,
                                                   float* __restrict__ out) {
    const int b    = threadIdx.x;
    const int wave = b >> 6;
    const int lane = b & 63;
    __shared__ float red[4];

    const float cnx = pB[0 * 512 + 2 * b] + pB[0 * 512 + 2 * b + 1];
    const float cny = pB[1 * 512 + 2 * b] + pB[1 * 512 + 2 * b + 1];
    const float cd  = pB[2 * 512 + 2 * b] + pB[2 * 512 + 2 * b + 1];
    const float pnx = pB[3 * 512 + 2 * b] + pB[3 * 512 + 2 * b + 1];
    const float pny = pB[4 * 512 + 2 * b] + pB[4 * 512 + 2 * b + 1];
    const float pd  = pB[5 * 512 + 2 * b] + pB[5 * 512 + 2 * b + 1];
    const float pt  = acc[b * 16 + 10];
    const float pxs = acc[b * 16 + 11];
    const float pys = acc[b * 16 + 12];

    const float comx  = cnx / cd;
    const float comy  = cny / cd;
    const float copx  = pnx / (pd + 1e-6f);
    const float copy_ = pny / (pd + 1e-6f);

    out[1 + 2 * b + 0] = comx * 48.0f;
    out[1 + 2 * b + 1] = (59.0f / 33.0f - comy) * 33.0f;
    out[1 + 2 * NB + 2 * b + 0] = (copx + 18.0f / 78.74f) * (100.0f * 0.7874f);
    out[1 + 2 * NB + 2 * b + 1] = (86.0f / 78.74f - copy_) * (100.0f * 0.7874f);

    const float total = (pt == 0.0f) ? 1e-8f : pt;
    const float xc = pxs / total;
    const float yc = pys / total;
    const float pcopx = 0.01f * (xc - 18.0f) / 0.7874f;
    const float pcopy = 0.01f * (86.0f - yc) / 0.7874f;

    const float dx = comx - pcopx;
    const float dy = comy - pcopy;
    float v = sqrtf(dx * dx + dy * dy);

    v = wred(v);
    if (lane == 0) red[wave] = v;
    __syncthreads();
    if (b == 0) out[0] = (red[0] + red[1] + red[2] + red[3]) * (1.0f / NB);
}

extern "C" void kernel_launch(void* const* d_in, const int* in_sizes, int n_in,
                              void* d_out, int out_size, void* d_ws, size_t ws_size,
                              hipStream_t stream) {
    const float* vertices    = (const float*)d_in[0];
    const float* pressure    = (const float*)d_in[1];
    const float* bary_w      = (const float*)d_in[2];
    const int*   faces       = (const int*)d_in[3];
    const int*   face_sample = (const int*)d_in[4];
    const int*   face_part   = (const int*)d_in[5];
    float* out = (float*)d_out;
    char*  ws  = (char*)d_ws;

    float*  acc  = (float*)(ws + WS_ACC_OFF);
    float*  pB   = (float*)(ws + WS_PB_OFF);
    int4*   tabF = (int4*)(ws + WS_TABF_OFF);
    int4*   tabS = (int4*)(ws + WS_TABS_OFF);
    float4* tabW = (float4*)(ws + WS_TABW_OFF);

    build_tabs<<<(NHDP + 255) / 256, 256, 0, stream>>>(faces, face_part, face_sample,
                                                       bary_w, tabF, tabS, tabW);
    kA<<<NB, 1024, 0, stream>>>(vertices, pressure, tabF, acc);
    kB<<<NB * 2, 1024, 0, stream>>>(vertices, tabS, tabW, acc, pB);
    stab_finish<<<1, 256, 0, stream>>>(acc, pB, out);
}

// Round 16
// 33.195 us; speedup vs baseline: 1.5516x; 1.2752x over previous
//
#include <hip/hip_runtime.h>
#include <math.h>

#define NB 256
#define NV 6890
#define NF 13776
#define NFP 16384               // faces padded to 4 * 4096, pad part = 15
#define NHD 20000
#define NHDP 20480              // samples padded to 5 * 4096, pad mask = 0
#define NPARTS 10
#define PY 120
#define PX 40
#define THREADS 1024
#define NWAVES (THREADS / 64)

// d_ws layout (bytes):
//   [0, 1024)            : per-batch distances (NB floats)
//   [1024, +NFP*16)      : face table   int4{i0,i1,i2,part}   (pads part=15)
//   [.., +NHDP*16)       : sample table int4{i0,i1,i2,part}   (pads {0,0,0,0})
//   [.., +NHDP*16)       : sample bary  float4{w0,w1,w2,mask} (pads mask=0)
#define WS_DIST_OFF  0
#define WS_TABF_OFF  1024
#define WS_TABS_OFF  (WS_TABF_OFF + NFP * 16)
#define WS_TABW_OFF  (WS_TABS_OFF + NHDP * 16)
#define WS_NEEDED    (WS_TABW_OFF + NHDP * 16)

__device__ __forceinline__ float wred(float v) {
#pragma unroll
    for (int off = 32; off; off >>= 1) v += __shfl_down(v, off, 64);
    return v;
}

__global__ __launch_bounds__(256) void build_tabs(const int* __restrict__ faces,
                                                  const int* __restrict__ face_part,
                                                  const int* __restrict__ face_sample,
                                                  const float* __restrict__ bary_w,
                                                  int4* __restrict__ tabF,
                                                  int4* __restrict__ tabS,
                                                  float4* __restrict__ tabW) {
    const int i = blockIdx.x * 256 + threadIdx.x;
    if (i < NF)
        tabF[i] = make_int4(faces[3 * i + 0], faces[3 * i + 1], faces[3 * i + 2], face_part[i]);
    else if (i < NFP)
        tabF[i] = make_int4(0, 0, 0, 15);            // pad: part 15 never accumulated
    if (i < NHD) {
        const int fs = face_sample[i];
        tabS[i] = make_int4(faces[3 * fs + 0], faces[3 * fs + 1], faces[3 * fs + 2],
                            face_part[fs]);
        tabW[i] = make_float4(bary_w[3 * i + 0], bary_w[3 * i + 1], bary_w[3 * i + 2], 1.0f);
    } else if (i < NHDP) {
        tabS[i] = make_int4(0, 0, 0, 0);
        tabW[i] = make_float4(0.0f, 0.0f, 0.0f, 0.0f);   // mask=0: contributes nothing
    }
}

__device__ __forceinline__ float tet_of(const float2* __restrict__ svxy,
                                        const float* __restrict__ svz, int4 q) {
    const float2 a = svxy[q.x];
    const float2 b = svxy[q.y];
    const float2 c = svxy[q.z];
    const float az = svz[q.x], bz = svz[q.y], cz = svz[q.z];
    return (a.x * (b.y * cz - bz * c.y) + a.y * (bz * c.x - b.x * cz) +
            az * (b.x * c.y - b.y * c.x)) * (1.0f / 6.0f);
}

template <bool TAB>
__global__ __launch_bounds__(THREADS, 4) void stab_main(
    const float* __restrict__ vertices,    // [NB, NV, 3]
    const float* __restrict__ pressure,    // [NB, PY, PX]
    const float* __restrict__ bary_w,      // [NHD, 3]
    const int*   __restrict__ faces,       // [NF, 3]
    const int*   __restrict__ face_sample, // [NHD]
    const int*   __restrict__ face_part,   // [NF]
    const int4*  __restrict__ tabF,        // [NFP]
    const int4*  __restrict__ tabS,        // [NHDP]
    const float4* __restrict__ tabW,       // [NHDP]
    float* __restrict__ out,
    float* __restrict__ dist)
{
    const int b    = blockIdx.x;
    const int tid  = threadIdx.x;
    const int wave = tid >> 6;
    const int lane = tid & 63;

    __shared__ float2 svxy[NV];           // 55120 B: b64 gathers, half the instrs
    __shared__ float  svz[NV];            // 27560 B
    __shared__ float  red[NWAVES][12];
    __shared__ float  ppv[NPARTS];        // one address per bank: broadcast, conflict-free

    // ---- stage vertices[b] into LDS (xy packed, z separate) ----
    const float* vb = vertices + (size_t)b * (NV * 3);
    for (int v = tid; v < NV; v += THREADS) {
        svxy[v] = make_float2(vb[3 * v + 0], vb[3 * v + 1]);
        svz[v]  = vb[3 * v + 2];
    }
    __syncthreads();

    // ---- Phase A: tet volumes -> per-part sums (4 independent chains / iter) ----
    float pv[NPARTS];
#pragma unroll
    for (int p = 0; p < NPARTS; ++p) pv[p] = 0.0f;

    if constexpr (TAB) {
        for (int f0 = tid; f0 < NFP; f0 += 4 * THREADS) {
            const int4 q0 = tabF[f0];
            const int4 q1 = tabF[f0 + THREADS];
            const int4 q2 = tabF[f0 + 2 * THREADS];
            const int4 q3 = tabF[f0 + 3 * THREADS];
            const float t0 = tet_of(svxy, svz, q0);
            const float t1 = tet_of(svxy, svz, q1);
            const float t2 = tet_of(svxy, svz, q2);
            const float t3 = tet_of(svxy, svz, q3);
#pragma unroll
            for (int p = 0; p < NPARTS; ++p) {
                pv[p] += (q0.w == p) ? t0 : 0.0f;
                pv[p] += (q1.w == p) ? t1 : 0.0f;
                pv[p] += (q2.w == p) ? t2 : 0.0f;
                pv[p] += (q3.w == p) ? t3 : 0.0f;
            }
        }
    } else {
        for (int f = tid; f < NF; f += THREADS) {
            const int4 q = make_int4(faces[3 * f + 0], faces[3 * f + 1], faces[3 * f + 2],
                                     face_part[f]);
            const float t = tet_of(svxy, svz, q);
#pragma unroll
            for (int p = 0; p < NPARTS; ++p) pv[p] += (q.w == p) ? t : 0.0f;
        }
    }
#pragma unroll
    for (int p = 0; p < NPARTS; ++p) {
        const float r = wred(pv[p]);
        if (lane == 0) red[wave][p] = r;
    }
    __syncthreads();
    if (tid < NPARTS) {
        float s = 0.0f;
#pragma unroll
        for (int w = 0; w < NWAVES; ++w) s += red[w][tid];
        ppv[tid] = s;
    }
    __syncthreads();

    // ---- Phase B: blended samples -> COM + weighted-CoP sums ----
    float cnx = 0.f, cny = 0.f, cd = 0.f;
    float pnx = 0.f, pny = 0.f, pd = 0.f;

    if constexpr (TAB) {
        for (int n0 = tid; n0 < NHDP; n0 += 4 * THREADS) {
            const int4   q0 = tabS[n0];
            const int4   q1 = tabS[n0 + THREADS];
            const int4   q2 = tabS[n0 + 2 * THREADS];
            const int4   q3 = tabS[n0 + 3 * THREADS];
            const float4 w0 = tabW[n0];
            const float4 w1 = tabW[n0 + THREADS];
            const float4 w2 = tabW[n0 + 2 * THREADS];
            const float4 w3 = tabW[n0 + 3 * THREADS];

            const float2 a0 = svxy[q0.x], b0 = svxy[q0.y], c0 = svxy[q0.z];
            const float2 a1 = svxy[q1.x], b1 = svxy[q1.y], c1 = svxy[q1.z];
            const float2 a2 = svxy[q2.x], b2 = svxy[q2.y], c2 = svxy[q2.z];
            const float2 a3 = svxy[q3.x], b3 = svxy[q3.y], c3 = svxy[q3.z];

            const float hx0 = w0.x * a0.x + w0.y * b0.x + w0.z * c0.x;
            const float hy0 = w0.x * a0.y + w0.y * b0.y + w0.z * c0.y;
            const float hx1 = w1.x * a1.x + w1.y * b1.x + w1.z * c1.x;
            const float hy1 = w1.x * a1.y + w1.y * b1.y + w1.z * c1.y;
            const float hx2 = w2.x * a2.x + w2.y * b2.x + w2.z * c2.x;
            const float hy2 = w2.x * a2.y + w2.y * b2.y + w2.z * c2.y;
            const float hx3 = w3.x * a3.x + w3.y * b3.x + w3.z * c3.x;
            const float hy3 = w3.x * a3.y + w3.y * b3.y + w3.z * c3.y;

            const float vol0 = ppv[q0.w] * w0.w;
            const float vol1 = ppv[q1.w] * w1.w;
            const float vol2 = ppv[q2.w] * w2.w;
            const float vol3 = ppv[q3.w] * w3.w;

            const float pw0 = ((hy0 < 0.0f) ? (1.0f - 100.0f * hy0) : __expf(-10.0f * hy0)) * w0.w;
            const float pw1 = ((hy1 < 0.0f) ? (1.0f - 100.0f * hy1) : __expf(-10.0f * hy1)) * w1.w;
            const float pw2 = ((hy2 < 0.0f) ? (1.0f - 100.0f * hy2) : __expf(-10.0f * hy2)) * w2.w;
            const float pw3 = ((hy3 < 0.0f) ? (1.0f - 100.0f * hy3) : __expf(-10.0f * hy3)) * w3.w;

            cnx += hx0 * vol0 + hx1 * vol1 + hx2 * vol2 + hx3 * vol3;
            cny += hy0 * vol0 + hy1 * vol1 + hy2 * vol2 + hy3 * vol3;
            cd  += vol0 + vol1 + vol2 + vol3;
            pnx += hx0 * pw0 + hx1 * pw1 + hx2 * pw2 + hx3 * pw3;
            pny += hy0 * pw0 + hy1 * pw1 + hy2 * pw2 + hy3 * pw3;
            pd  += pw0 + pw1 + pw2 + pw3;
        }
    } else {
        for (int n = tid; n < NHD; n += THREADS) {
            const int fs = face_sample[n];
            const int i0 = faces[3 * fs + 0], i1 = faces[3 * fs + 1], i2 = faces[3 * fs + 2];
            const float w0 = bary_w[3 * n + 0], w1 = bary_w[3 * n + 1], w2 = bary_w[3 * n + 2];
            const float2 a = svxy[i0], bb = svxy[i1], c = svxy[i2];
            const float hx = w0 * a.x + w1 * bb.x + w2 * c.x;
            const float hy = w0 * a.y + w1 * bb.y + w2 * c.y;
            const float vol = ppv[face_part[fs]];
            cnx += hx * vol; cny += hy * vol; cd += vol;
            const float pw = (hy < 0.0f) ? (1.0f - 100.0f * hy) : __expf(-10.0f * hy);
            pnx += hx * pw; pny += hy * pw; pd += pw;
        }
    }

    // ---- pressure moments (float4) ----
    float pt = 0.f, pxs = 0.f, pys = 0.f;
    const float4* pb4 = (const float4*)(pressure + (size_t)b * (PY * PX));
    for (int i = tid; i < (PY * PX) / 4; i += THREADS) {
        const float4 v = pb4[i];
        const int idx = 4 * i;
        const float xb = (float)(idx % PX);
        const float yb = (float)(idx / PX);
        const float srow = v.x + v.y + v.z + v.w;
        pt  += srow;
        pxs += v.x * xb + v.y * (xb + 1.0f) + v.z * (xb + 2.0f) + v.w * (xb + 3.0f);
        pys += srow * yb;
    }

    // ---- block reduction of 9 scalars ----
    float vals[9] = {cnx, cny, cd, pnx, pny, pd, pt, pxs, pys};
#pragma unroll
    for (int k = 0; k < 9; ++k) {
        const float r = wred(vals[k]);
        if (lane == 0) red[wave][k] = r;
    }
    __syncthreads();

    if (tid == 0) {
        float s[9];
#pragma unroll
        for (int k = 0; k < 9; ++k) {
            float acc = 0.0f;
#pragma unroll
            for (int w = 0; w < NWAVES; ++w) acc += red[w][k];
            s[k] = acc;
        }
        const float comx  = s[0] / s[2];
        const float comy  = s[1] / s[2];
        const float copx  = s[3] / (s[5] + 1e-6f);
        const float copy_ = s[4] / (s[5] + 1e-6f);

        out[1 + 2 * b + 0] = comx * 48.0f;
        out[1 + 2 * b + 1] = (59.0f / 33.0f - comy) * 33.0f;
        out[1 + 2 * NB + 2 * b + 0] = (copx + 18.0f / 78.74f) * (100.0f * 0.7874f);
        out[1 + 2 * NB + 2 * b + 1] = (86.0f / 78.74f - copy_) * (100.0f * 0.7874f);

        const float total = (s[6] == 0.0f) ? 1e-8f : s[6];
        const float xc = s[7] / total;
        const float yc = s[8] / total;
        const float pcopx = 0.01f * (xc - 18.0f) / 0.7874f;
        const float pcopy = 0.01f * (86.0f - yc) / 0.7874f;

        const float dx = comx - pcopx;
        const float dy = comy - pcopy;
        dist[b] = sqrtf(dx * dx + dy * dy);
    }
}

__global__ __launch_bounds__(256) void stab_reduce(const float* __restrict__ dist,
                                                   float* __restrict__ out) {
    const int tid = threadIdx.x;
    float v = dist[tid];
    v = wred(v);
    __shared__ float red[4];
    if ((tid & 63) == 0) red[tid >> 6] = v;
    __syncthreads();
    if (tid == 0) out[0] = (red[0] + red[1] + red[2] + red[3]) * (1.0f / 256.0f);
}

extern "C" void kernel_launch(void* const* d_in, const int* in_sizes, int n_in,
                              void* d_out, int out_size, void* d_ws, size_t ws_size,
                              hipStream_t stream) {
    const float* vertices    = (const float*)d_in[0];
    const float* pressure    = (const float*)d_in[1];
    const float* bary_w      = (const float*)d_in[2];
    const int*   faces       = (const int*)d_in[3];
    const int*   face_sample = (const int*)d_in[4];
    const int*   face_part   = (const int*)d_in[5];
    float* out = (float*)d_out;
    char*  ws  = (char*)d_ws;

    float* dist = (float*)(ws + WS_DIST_OFF);

    if (ws_size >= (size_t)WS_NEEDED) {
        int4*   tabF = (int4*)(ws + WS_TABF_OFF);
        int4*   tabS = (int4*)(ws + WS_TABS_OFF);
        float4* tabW = (float4*)(ws + WS_TABW_OFF);
        build_tabs<<<(NHDP + 255) / 256, 256, 0, stream>>>(faces, face_part, face_sample,
                                                           bary_w, tabF, tabS, tabW);
        stab_main<true><<<NB, THREADS, 0, stream>>>(vertices, pressure, bary_w, faces,
                                                    face_sample, face_part, tabF, tabS, tabW,
                                                    out, dist);
    } else {
        stab_main<false><<<NB, THREADS, 0, stream>>>(vertices, pressure, bary_w, faces,
                                                     face_sample, face_part, nullptr, nullptr,
                                                     nullptr, out, dist);
    }
    stab_reduce<<<1, 256, 0, stream>>>(dist, out);
}